// Round 3
// baseline (383.305 us; speedup 1.0000x reference)
//
#include <hip/hip_runtime.h>

#define NN 50000
#define EE 1600000
#define NEG_SLOPE 0.2f

__device__ __forceinline__ void fma4(float4& a, float s, const float4& b) {
  a.x = fmaf(s, b.x, a.x);
  a.y = fmaf(s, b.y, a.y);
  a.z = fmaf(s, b.z, a.z);
  a.w = fmaf(s, b.w, a.w);
}

// ---- P1: feat = h @ W + fused el/er epilogue + fused in-degree histogram ----
// deg (and counter) are pre-zeroed by a hipMemsetAsync before this kernel.
__global__ __launch_bounds__(256) void k_feat(const float* __restrict__ hg,
                                              const float* __restrict__ Wg,
                                              const float* __restrict__ attn_l,
                                              const float* __restrict__ attn_r,
                                              const int* __restrict__ dstg,
                                              float* __restrict__ feat,
                                              float* __restrict__ el,
                                              float* __restrict__ er,
                                              int* __restrict__ deg) {
  __shared__ float sH[64 * 128];   // 32 KB
  __shared__ float sW[128 * 64];   // 32 KB
  int t = threadIdx.x;
  // fused histogram: 782*256 = 200192 threads, 8 strided passes over E
  for (int i = blockIdx.x * 256 + t; i < EE; i += 782 * 256)
    atomicAdd(&deg[dstg[i]], 1);
  int r0 = blockIdx.x * 64;
  const float4* hg4 = (const float4*)hg;
#pragma unroll
  for (int i = 0; i < 8; i++) {
    int f = t + i * 256;
    int row = f >> 5, kq = f & 31;
    int r = r0 + row;
    float4 v = make_float4(0.f, 0.f, 0.f, 0.f);
    if (r < NN) v = hg4[(size_t)r * 32 + kq];
    *(float4*)&sH[row * 128 + kq * 4] = v;
    ((float4*)sW)[f] = ((const float4*)Wg)[f];
  }
  __syncthreads();
  int tx = t & 15, ty = t >> 4;
  float4 acc[4];
#pragma unroll
  for (int i = 0; i < 4; i++) acc[i] = make_float4(0.f, 0.f, 0.f, 0.f);
  const float4* sW4 = (const float4*)sW;
  for (int k = 0; k < 128; k += 4) {
    float4 w0 = sW4[(k + 0) * 16 + tx];
    float4 w1 = sW4[(k + 1) * 16 + tx];
    float4 w2 = sW4[(k + 2) * 16 + tx];
    float4 w3 = sW4[(k + 3) * 16 + tx];
#pragma unroll
    for (int i = 0; i < 4; i++) {
      float4 hv = *(const float4*)&sH[(ty * 4 + i) * 128 + k];
      fma4(acc[i], hv.x, w0);
      fma4(acc[i], hv.y, w1);
      fma4(acc[i], hv.z, w2);
      fma4(acc[i], hv.w, w3);
    }
  }
  int head = tx >> 2;
  float4 al = ((const float4*)attn_l)[tx];
  float4 ar = ((const float4*)attn_r)[tx];
#pragma unroll
  for (int i = 0; i < 4; i++) {
    int r = r0 + ty * 4 + i;
    float sl = acc[i].x * al.x + acc[i].y * al.y + acc[i].z * al.z + acc[i].w * al.w;
    float sr = acc[i].x * ar.x + acc[i].y * ar.y + acc[i].z * ar.z + acc[i].w * ar.w;
    sl += __shfl_xor(sl, 1); sl += __shfl_xor(sl, 2);
    sr += __shfl_xor(sr, 1); sr += __shfl_xor(sr, 2);
    if (r < NN) {
      ((float4*)feat)[(size_t)r * 16 + tx] = acc[i];
      if ((tx & 3) == 0) {
        el[r * 4 + head] = sl;
        er[r * 4 + head] = sr;
      }
    }
  }
}

// ---- P2: offsets/cursor via wave-prefix + global atomic; block 0 computes c ----
__global__ __launch_bounds__(256) void k_off(const float* __restrict__ We,
                                             const float* __restrict__ ae,
                                             float* __restrict__ c,
                                             const int* __restrict__ deg,
                                             int* __restrict__ offsets,
                                             int* __restrict__ cursor,
                                             int* __restrict__ counter) {
  int t = threadIdx.x;
  if (blockIdx.x == 0) {
    // c[k][h] = sum_d We[k, h*16+d] * attn_e[h, d]   (64 k x 4 h = 256 threads)
    int k = t >> 2, hh = t & 3;
    const float4* we4 = (const float4*)(We + (size_t)k * 64 + hh * 16);
    const float4* ae4 = (const float4*)(ae + hh * 16);
    float s = 0.f;
#pragma unroll
    for (int i = 0; i < 4; i++) {
      float4 v = we4[i];
      float4 a = ae4[i];
      s += v.x * a.x + v.y * a.y + v.z * a.z + v.w * a.w;
    }
    c[k * 4 + hh] = s;
  }
  int n = blockIdx.x * 256 + t;
  int lane = t & 63;
  int d = (n < NN) ? deg[n] : 0;
  int x = d;
#pragma unroll
  for (int dd = 1; dd < 64; dd <<= 1) {
    int y = __shfl_up(x, dd);
    if (lane >= dd) x += y;
  }
  int total = __shfl(x, 63);
  int base = 0;
  if (lane == 63) base = atomicAdd(counter, total);
  base = __shfl(base, 63);
  int offv = base + x - d;
  if (n < NN) {
    offsets[n] = offv;
    cursor[n] = offv;
  }
}

// ---- P3: counting-sort edge ids by destination ----
__global__ __launch_bounds__(256) void k_sort(const int* __restrict__ dstg,
                                              int* __restrict__ cursor,
                                              int* __restrict__ eid) {
  int e = blockIdx.x * 256 + threadIdx.x;   // EE % 256 == 0
  int d = dstg[e];
  int slot = atomicAdd(&cursor[d], 1);
  eid[slot] = e;
}

// ---- P4: fused edge-logit + softmax + aggregation + ELU ----
// One wave per node. 8 lanes per edge (8 edges in flight per iteration):
// lane = eg*8 + g8; g8 owns k-slice [g8*8, g8*8+8) and output cols [g8*8, g8*8+8).
__global__ __launch_bounds__(64) void k_aggr(const int* __restrict__ offsets,
                                             const int* __restrict__ deg,
                                             const int* __restrict__ csr_eid,
                                             const int* __restrict__ srcg,
                                             const float* __restrict__ ef,
                                             const float* __restrict__ c,
                                             const float* __restrict__ el,
                                             const float* __restrict__ er,
                                             const float* __restrict__ feat,
                                             float* __restrict__ out) {
  __shared__ int seid[64];
  __shared__ int ssrc[64];
  __shared__ float4 sel4[64];
  int n = blockIdx.x;
  int lane = threadIdx.x;
  int g8 = lane & 7;     // k/col slice
  int eg = lane >> 3;    // edge subgroup
  int hd = g8 >> 1;      // head of this lane's 8 output cols
  int off = offsets[n];
  int dg = deg[n];
  // per-lane c slice: c[k][0..3] for k = g8*8 + j
  float4 c0[8];
#pragma unroll
  for (int j = 0; j < 8; j++) c0[j] = ((const float4*)c)[g8 * 8 + j];
  float4 er4 = ((const float4*)er)[n];
  float erh = (hd == 0) ? er4.x : (hd == 1) ? er4.y : (hd == 2) ? er4.z : er4.w;
  float4 f0 = make_float4(0.f, 0.f, 0.f, 0.f);
  float4 f1 = make_float4(0.f, 0.f, 0.f, 0.f);
  float dacc = 0.f;
  for (int b = 0; b < dg; b += 64) {
    int cnt = min(64, dg - b);
    if (lane < cnt) {
      int e = csr_eid[off + b + lane];
      int sr = srcg[e];
      seid[lane] = e;
      ssrc[lane] = sr;
      sel4[lane] = ((const float4*)el)[sr];
    }
    __syncthreads();
    int qmax = (cnt + 7) >> 3;
    for (int q = 0; q < qmax; q++) {
      int ei = q * 8 + eg;
      bool valid = ei < cnt;
      int eic = valid ? ei : (cnt - 1);
      int e = seid[eic];
      int sr = ssrc[eic];
      float elh = ((const float*)&sel4[eic])[hd];
      const float4* e4 = (const float4*)(ef + (size_t)e * 64 + g8 * 8);
      float4 a0 = e4[0], a1 = e4[1];
      float4 s4 = make_float4(0.f, 0.f, 0.f, 0.f);
      fma4(s4, a0.x, c0[0]); fma4(s4, a0.y, c0[1]);
      fma4(s4, a0.z, c0[2]); fma4(s4, a0.w, c0[3]);
      fma4(s4, a1.x, c0[4]); fma4(s4, a1.y, c0[5]);
      fma4(s4, a1.z, c0[6]); fma4(s4, a1.w, c0[7]);
#pragma unroll
      for (int m = 1; m < 8; m <<= 1) {
        s4.x += __shfl_xor(s4.x, m);
        s4.y += __shfl_xor(s4.y, m);
        s4.z += __shfl_xor(s4.z, m);
        s4.w += __shfl_xor(s4.w, m);
      }
      float eeh = (hd == 0) ? s4.x : (hd == 1) ? s4.y : (hd == 2) ? s4.z : s4.w;
      float lg = eeh + elh + erh;
      float lv = (lg > 0.f) ? lg : NEG_SLOPE * lg;
      float p = valid ? __expf(lv) : 0.f;
      dacc += p;
      const float4* fv = (const float4*)(feat + (size_t)sr * 64 + g8 * 8);
      fma4(f0, p, fv[0]);
      fma4(f1, p, fv[1]);
    }
    __syncthreads();
  }
  // reduce across edge subgroups (lane bits 3,4,5); col slices untouched
#pragma unroll
  for (int m = 8; m < 64; m <<= 1) {
    f0.x += __shfl_xor(f0.x, m); f0.y += __shfl_xor(f0.y, m);
    f0.z += __shfl_xor(f0.z, m); f0.w += __shfl_xor(f0.w, m);
    f1.x += __shfl_xor(f1.x, m); f1.y += __shfl_xor(f1.y, m);
    f1.z += __shfl_xor(f1.z, m); f1.w += __shfl_xor(f1.w, m);
    dacc += __shfl_xor(dacc, m);
  }
  float inv = 1.f / fmaxf(dacc, 1e-16f);
  f0.x *= inv; f0.y *= inv; f0.z *= inv; f0.w *= inv;
  f1.x *= inv; f1.y *= inv; f1.z *= inv; f1.w *= inv;
  f0.x = (f0.x > 0.f) ? f0.x : expm1f(f0.x);
  f0.y = (f0.y > 0.f) ? f0.y : expm1f(f0.y);
  f0.z = (f0.z > 0.f) ? f0.z : expm1f(f0.z);
  f0.w = (f0.w > 0.f) ? f0.w : expm1f(f0.w);
  f1.x = (f1.x > 0.f) ? f1.x : expm1f(f1.x);
  f1.y = (f1.y > 0.f) ? f1.y : expm1f(f1.y);
  f1.z = (f1.z > 0.f) ? f1.z : expm1f(f1.z);
  f1.w = (f1.w > 0.f) ? f1.w : expm1f(f1.w);
  if (eg == 0) {
    float4* o4 = (float4*)(out + (size_t)n * 64 + g8 * 8);
    o4[0] = f0;
    o4[1] = f1;
  }
}

extern "C" void kernel_launch(void* const* d_in, const int* in_sizes, int n_in,
                              void* d_out, int out_size, void* d_ws, size_t ws_size,
                              hipStream_t stream) {
  const float* h       = (const float*)d_in[0];
  const float* edge_ft = (const float*)d_in[1];
  const int*   src     = (const int*)d_in[2];
  const int*   dst     = (const int*)d_in[3];
  const float* W       = (const float*)d_in[4];
  const float* We      = (const float*)d_in[5];
  const float* attn_l  = (const float*)d_in[6];
  const float* attn_r  = (const float*)d_in[7];
  const float* attn_e  = (const float*)d_in[8];
  float* out = (float*)d_out;

  char* ws = (char*)d_ws;
  float* feat    = (float*)ws;                    // N*64 f32 = 12,800,000 B
  float* el      = feat + (size_t)NN * 64;        // N*4      =    800,000 B
  float* er      = el + NN * 4;                   //               800,000 B
  float* c       = er + NN * 4;                   // 256 f32  =      1,024 B
  int*   deg     = (int*)(c + 256);               // N        =    200,000 B
  int*   counter = deg + NN;                      //                     4 B
  int*   offsets = counter + 1;                   //               200,000 B
  int*   cursor  = offsets + NN;                  //               200,000 B
  int*   csr_eid = cursor + NN;                   // E        =  6,400,000 B
  if (ws_size < (size_t)22000000) return;

  hipMemsetAsync(deg, 0, (NN + 1) * sizeof(int), stream);  // deg + counter
  k_feat<<<(NN + 63) / 64, 256, 0, stream>>>(h, W, attn_l, attn_r, dst,
                                             feat, el, er, deg);
  k_off<<<(NN + 255) / 256, 256, 0, stream>>>(We, attn_e, c, deg,
                                              offsets, cursor, counter);
  k_sort<<<EE / 256, 256, 0, stream>>>(dst, cursor, csr_eid);
  k_aggr<<<NN, 64, 0, stream>>>(offsets, deg, csr_eid, src, edge_ft, c,
                                el, er, feat, out);
}

// Round 4
// 364.615 us; speedup vs baseline: 1.0513x; 1.0513x over previous
//
#include <hip/hip_runtime.h>

#define NN 50000
#define EE 1600000
#define NEG_SLOPE 0.2f

__device__ __forceinline__ void fma4(float4& a, float s, const float4& b) {
  a.x = fmaf(s, b.x, a.x);
  a.y = fmaf(s, b.y, a.y);
  a.z = fmaf(s, b.z, a.z);
  a.w = fmaf(s, b.w, a.w);
}

// ---- P1: feat = h @ W + fused el/er epilogue + fused in-degree histogram ----
// deg and counter are pre-zeroed by hipMemsetAsync before this kernel.
__global__ __launch_bounds__(256) void k_feat(const float* __restrict__ hg,
                                              const float* __restrict__ Wg,
                                              const float* __restrict__ attn_l,
                                              const float* __restrict__ attn_r,
                                              const int* __restrict__ dstg,
                                              float* __restrict__ feat,
                                              float* __restrict__ el,
                                              float* __restrict__ er,
                                              int* __restrict__ deg) {
  __shared__ float sH[64 * 128];   // 32 KB
  __shared__ float sW[128 * 64];   // 32 KB
  int t = threadIdx.x;
  // fused histogram: 782*256 = 200192 threads, ~8 strided passes over E
  for (int i = blockIdx.x * 256 + t; i < EE; i += 782 * 256)
    atomicAdd(&deg[dstg[i]], 1);
  int r0 = blockIdx.x * 64;
  const float4* hg4 = (const float4*)hg;
#pragma unroll
  for (int i = 0; i < 8; i++) {
    int f = t + i * 256;
    int row = f >> 5, kq = f & 31;
    int r = r0 + row;
    float4 v = make_float4(0.f, 0.f, 0.f, 0.f);
    if (r < NN) v = hg4[(size_t)r * 32 + kq];
    *(float4*)&sH[row * 128 + kq * 4] = v;
    ((float4*)sW)[f] = ((const float4*)Wg)[f];
  }
  __syncthreads();
  int tx = t & 15, ty = t >> 4;
  float4 acc[4];
#pragma unroll
  for (int i = 0; i < 4; i++) acc[i] = make_float4(0.f, 0.f, 0.f, 0.f);
  const float4* sW4 = (const float4*)sW;
  for (int k = 0; k < 128; k += 4) {
    float4 w0 = sW4[(k + 0) * 16 + tx];
    float4 w1 = sW4[(k + 1) * 16 + tx];
    float4 w2 = sW4[(k + 2) * 16 + tx];
    float4 w3 = sW4[(k + 3) * 16 + tx];
#pragma unroll
    for (int i = 0; i < 4; i++) {
      float4 hv = *(const float4*)&sH[(ty * 4 + i) * 128 + k];
      fma4(acc[i], hv.x, w0);
      fma4(acc[i], hv.y, w1);
      fma4(acc[i], hv.z, w2);
      fma4(acc[i], hv.w, w3);
    }
  }
  int head = tx >> 2;
  float4 al = ((const float4*)attn_l)[tx];
  float4 ar = ((const float4*)attn_r)[tx];
#pragma unroll
  for (int i = 0; i < 4; i++) {
    int r = r0 + ty * 4 + i;
    float sl = acc[i].x * al.x + acc[i].y * al.y + acc[i].z * al.z + acc[i].w * al.w;
    float sr = acc[i].x * ar.x + acc[i].y * ar.y + acc[i].z * ar.z + acc[i].w * ar.w;
    sl += __shfl_xor(sl, 1); sl += __shfl_xor(sl, 2);
    sr += __shfl_xor(sr, 1); sr += __shfl_xor(sr, 2);
    if (r < NN) {
      ((float4*)feat)[(size_t)r * 16 + tx] = acc[i];
      if ((tx & 3) == 0) {
        el[r * 4 + head] = sl;
        er[r * 4 + head] = sr;
      }
    }
  }
}

// ---- P2: offsets/cursor via wave-prefix + global atomic; block 0 computes c ----
__global__ __launch_bounds__(256) void k_off(const float* __restrict__ We,
                                             const float* __restrict__ ae,
                                             float* __restrict__ c,
                                             const int* __restrict__ deg,
                                             int* __restrict__ offsets,
                                             int* __restrict__ cursor,
                                             int* __restrict__ counter) {
  int t = threadIdx.x;
  if (blockIdx.x == 0) {
    int k = t >> 2, hh = t & 3;
    const float4* we4 = (const float4*)(We + (size_t)k * 64 + hh * 16);
    const float4* ae4 = (const float4*)(ae + hh * 16);
    float s = 0.f;
#pragma unroll
    for (int i = 0; i < 4; i++) {
      float4 v = we4[i];
      float4 a = ae4[i];
      s += v.x * a.x + v.y * a.y + v.z * a.z + v.w * a.w;
    }
    c[k * 4 + hh] = s;
  }
  int n = blockIdx.x * 256 + t;
  int lane = t & 63;
  int d = (n < NN) ? deg[n] : 0;
  int x = d;
#pragma unroll
  for (int dd = 1; dd < 64; dd <<= 1) {
    int y = __shfl_up(x, dd);
    if (lane >= dd) x += y;
  }
  int total = __shfl(x, 63);
  int base = 0;
  if (lane == 63) base = atomicAdd(counter, total);
  base = __shfl(base, 63);
  int offv = base + x - d;
  if (n < NN) {
    offsets[n] = offv;
    cursor[n] = offv;
  }
}

// ---- P3: edge pass — stream ef, p = exp(leakyrelu(logit)) sequential write,
//          plus eid counting-sort scatter (j==0 lane). 4 lanes/edge. ----
__global__ __launch_bounds__(256) void k_edge(const float* __restrict__ ef,
                                              const int* __restrict__ srcg,
                                              const int* __restrict__ dstg,
                                              const float* __restrict__ c,
                                              const float* __restrict__ el,
                                              const float* __restrict__ er,
                                              int* __restrict__ cursor,
                                              int* __restrict__ csr_eid,
                                              float* __restrict__ pexp) {
  __shared__ float4 sc[64];
  int t = threadIdx.x;
  if (t < 64) sc[t] = ((const float4*)c)[t];
  __syncthreads();
  int j = t & 3;                      // k-quarter AND head lane
  int e = blockIdx.x * 64 + (t >> 2); // EE % 64 == 0 -> no guard
  const float4* ef4 = (const float4*)(ef + (size_t)e * 64 + j * 16);
  float4 v0 = ef4[0], v1 = ef4[1], v2 = ef4[2], v3 = ef4[3];
  float4 acc = make_float4(0.f, 0.f, 0.f, 0.f);
  int kb = j * 16;
  fma4(acc, v0.x, sc[kb + 0]);  fma4(acc, v0.y, sc[kb + 1]);
  fma4(acc, v0.z, sc[kb + 2]);  fma4(acc, v0.w, sc[kb + 3]);
  fma4(acc, v1.x, sc[kb + 4]);  fma4(acc, v1.y, sc[kb + 5]);
  fma4(acc, v1.z, sc[kb + 6]);  fma4(acc, v1.w, sc[kb + 7]);
  fma4(acc, v2.x, sc[kb + 8]);  fma4(acc, v2.y, sc[kb + 9]);
  fma4(acc, v2.z, sc[kb + 10]); fma4(acc, v2.w, sc[kb + 11]);
  fma4(acc, v3.x, sc[kb + 12]); fma4(acc, v3.y, sc[kb + 13]);
  fma4(acc, v3.z, sc[kb + 14]); fma4(acc, v3.w, sc[kb + 15]);
#pragma unroll
  for (int m = 1; m < 4; m <<= 1) {
    acc.x += __shfl_xor(acc.x, m);
    acc.y += __shfl_xor(acc.y, m);
    acc.z += __shfl_xor(acc.z, m);
    acc.w += __shfl_xor(acc.w, m);
  }
  float eeh = (j == 0) ? acc.x : (j == 1) ? acc.y : (j == 2) ? acc.z : acc.w;
  int es = srcg[e];
  int ed = dstg[e];
  float lg = el[es * 4 + j] + er[ed * 4 + j] + eeh;
  float lv = (lg > 0.f) ? lg : NEG_SLOPE * lg;
  pexp[(size_t)e * 4 + j] = __expf(lv);      // coalesced sequential store
  if (j == 0) {
    int slot = atomicAdd(&cursor[ed], 1);
    csr_eid[slot] = e;                       // 4B scatter into 6.4MB (L3)
  }
}

// ---- P4: aggregation + softmax-normalize + ELU ----
// 256-thread blocks, 4 waves = 4 nodes per block; no LDS, no barriers.
// Per wave: lane owns output column `lane`; 16 edges staged per round via
// registers; inner loop broadcasts p/src with __shfl.
__global__ __launch_bounds__(256) void k_aggr(const int* __restrict__ offsets,
                                              const int* __restrict__ deg,
                                              const int* __restrict__ csr_eid,
                                              const int* __restrict__ srcg,
                                              const float* __restrict__ pexp,
                                              const float* __restrict__ feat,
                                              float* __restrict__ out) {
  int t = threadIdx.x;
  int w = t >> 6, lane = t & 63;
  int n = blockIdx.x * 4 + w;
  if (n >= NN) return;
  int off = offsets[n];
  int dg = deg[n];
  int hh = lane >> 4;          // head of this lane's output column
  int sub = lane >> 2;         // staging: edge slot 0..15
  int comp = lane & 3;         // staging: head component
  float facc = 0.f, dacc = 0.f;
  for (int b = 0; b < dg; b += 16) {
    int i = b + sub;
    float p_l = 0.f;
    int sr_l = 0;
    if (i < dg) {
      int e = csr_eid[off + i];
      p_l = pexp[(size_t)e * 4 + comp];
      sr_l = srcg[e];
    }
    dacc += p_l;
    int qcnt = min(16, dg - b);
    for (int q = 0; q < qcnt; q++) {
      float ph = __shfl(p_l, q * 4 + hh);
      int sq = __shfl(sr_l, q * 4);
      facc = fmaf(ph, feat[(size_t)sq * 64 + lane], facc);
    }
  }
  // denominator: sum over the 16 staging slots (lane bits 2..5), per head comp
#pragma unroll
  for (int m = 4; m < 64; m <<= 1) dacc += __shfl_xor(dacc, m);
  float denom = __shfl(dacc, hh);            // lane hh holds head hh's total
  float r = facc / fmaxf(denom, 1e-16f);
  out[(size_t)n * 64 + lane] = (r > 0.f) ? r : expm1f(r);
}

extern "C" void kernel_launch(void* const* d_in, const int* in_sizes, int n_in,
                              void* d_out, int out_size, void* d_ws, size_t ws_size,
                              hipStream_t stream) {
  const float* h       = (const float*)d_in[0];
  const float* edge_ft = (const float*)d_in[1];
  const int*   src     = (const int*)d_in[2];
  const int*   dst     = (const int*)d_in[3];
  const float* W       = (const float*)d_in[4];
  const float* We      = (const float*)d_in[5];
  const float* attn_l  = (const float*)d_in[6];
  const float* attn_r  = (const float*)d_in[7];
  const float* attn_e  = (const float*)d_in[8];
  float* out = (float*)d_out;

  char* ws = (char*)d_ws;
  float* feat    = (float*)ws;                    // N*64 f32 = 12,800,000 B
  float* el      = feat + (size_t)NN * 64;        // N*4      =    800,000 B
  float* er      = el + NN * 4;                   //               800,000 B
  float* c       = er + NN * 4;                   // 256 f32  =      1,024 B
  int*   deg     = (int*)(c + 256);               // N        =    200,000 B
  int*   counter = deg + NN;                      //                     4 B
  int*   offsets = counter + 1;                   //               200,000 B
  int*   cursor  = offsets + NN;                  //               200,000 B
  int*   csr_eid = cursor + NN;                   // E        =  6,400,000 B
  float* pexp    = (float*)(csr_eid + EE);        // E*4 f32  = 25,600,000 B
  if (ws_size < (size_t)48000000) return;

  hipMemsetAsync(deg, 0, (NN + 1) * sizeof(int), stream);  // deg + counter
  k_feat<<<(NN + 63) / 64, 256, 0, stream>>>(h, W, attn_l, attn_r, dst,
                                             feat, el, er, deg);
  k_off<<<(NN + 255) / 256, 256, 0, stream>>>(We, attn_e, c, deg,
                                              offsets, cursor, counter);
  k_edge<<<EE / 64, 256, 0, stream>>>(edge_ft, src, dst, c, el, er,
                                      cursor, csr_eid, pexp);
  k_aggr<<<(NN + 3) / 4, 256, 0, stream>>>(offsets, deg, csr_eid, src,
                                           pexp, feat, out);
}